// Round 4
// baseline (269.892 us; speedup 1.0000x reference)
//
#include <hip/hip_runtime.h>
#include <hip/hip_bf16.h>

// n=8192 rows, d=256 feat, 10 classes.
// loss = mean_i log1p(exp(0.5/0.7) * A_i * B_i)
//   A_i = sum_{j: y_j!=y_i} exp(sim_ij/0.7), B_i = sum_{j!=i: y_j==y_i} exp(-sim_ij/0.7)
//   sim = rownorm(P) @ rownorm(P)^T
//
// R4: occupancy fix. R2/R3 ran at 2 waves/SIMD (188 regs/lane) -> latency-
// bound (both pipes <12%); R3 additionally spilled (190 MB scratch writes).
// Now: 32x32x16 MFMA (acc=32 AGPR, fewer instrs, 2495 TF ceiling), wave tile
// 32x64, 512-thread blocks (wave grid 4x2 -> 128x128 tile), 2-tile col strip,
// __launch_bounds__(512,4) targeting <=128 regs -> 4 waves/SIMD. Classes
// packed 4/u32. Global-direct frag loads (L1 dedups cross-wave reuse),
// double-buffered. LDS merge of wc-pairs, 256 atomics/block.

#define NF 256
#define TINV (1.0f / 0.7f)

typedef __attribute__((ext_vector_type(8))) short short8;
typedef __attribute__((ext_vector_type(16))) float float16v;

// One wave per row: normalize to bf16. Also zeroes the accumulators.
__global__ __launch_bounds__(256)
void k_prep(const float* __restrict__ P, unsigned short* __restrict__ Pn,
            float* __restrict__ AB) {  // AB = Aacc||Bacc, 2n floats
    int wave = threadIdx.x >> 6, lane = threadIdx.x & 63;
    int row = blockIdx.x * 4 + wave;
    if (threadIdx.x < 8) AB[blockIdx.x * 8 + threadIdx.x] = 0.f;
    float4 v = *(const float4*)(P + (size_t)row * NF + lane * 4);
    float sq = v.x * v.x + v.y * v.y + v.z * v.z + v.w * v.w;
#pragma unroll
    for (int off = 32; off; off >>= 1) sq += __shfl_xor(sq, off, 64);
    float r = rsqrtf(sq);
    __hip_bfloat16 h0 = __float2bfloat16(v.x * r), h1 = __float2bfloat16(v.y * r),
                   h2 = __float2bfloat16(v.z * r), h3 = __float2bfloat16(v.w * r);
    ushort4 o = { *(unsigned short*)&h0, *(unsigned short*)&h1,
                  *(unsigned short*)&h2, *(unsigned short*)&h3 };
    *(ushort4*)(Pn + (size_t)row * NF + lane * 4) = o;
}

__global__ __launch_bounds__(512, 4)
void k_main(const unsigned short* __restrict__ Pn, const int* __restrict__ y,
            float* __restrict__ Aacc, float* __restrict__ Bacc) {
    const int I = blockIdx.x >> 5;           // 64 row panels of 128
    const int c = blockIdx.x & 31;           // 32 col strips of 256
    const int rb = I * 128, cb0 = c * 256;

    __shared__ int yc[256];
    __shared__ unsigned int ypk[32];         // row classes, 4 packed per u32
    __shared__ float mA[128], mB[128];

    const int tid = threadIdx.x;
    if (tid < 256) {
        yc[tid] = y[cb0 + tid];
    } else if (tid < 288) {
        int t = tid - 256;
        int4 v = *(const int4*)(y + rb + t * 4);
        ypk[t] = (unsigned)(v.x & 255) | ((unsigned)(v.y & 255) << 8) |
                 ((unsigned)(v.z & 255) << 16) | ((unsigned)(v.w & 255) << 24);
    }
    __syncthreads();

    const int lane = tid & 63, wave = tid >> 6;
    const int l31 = lane & 31, hi = lane >> 5;
    const int wr = wave >> 1, wc = wave & 1;  // 4 row-waves x 2 col-waves

    // 32x32x16 A-frag: m=l31, k=hi*8+j. B identical on row-major Pn (B^T).
    const unsigned short* pa = Pn + (size_t)(rb + wr * 32 + l31) * NF + hi * 8;

    unsigned int yp[4];
#pragma unroll
    for (int g = 0; g < 4; ++g) yp[g] = ypk[wr * 8 + g * 2 + hi];

    float rowA[16], rowB[16];
#pragma unroll
    for (int r = 0; r < 16; ++r) { rowA[r] = 0.f; rowB[r] = 0.f; }

#pragma unroll
    for (int jt = 0; jt < 2; ++jt) {
        const int cbl = jt * 128 + wc * 64;   // col offset within strip
        const unsigned short* pb0 = Pn + (size_t)(cb0 + cbl + l31) * NF + hi * 8;
        const unsigned short* pb1 = pb0 + (size_t)32 * NF;

        float16v acc[2];
#pragma unroll
        for (int t = 0; t < 2; ++t)
#pragma unroll
            for (int r = 0; r < 16; ++r) acc[t][r] = 0.f;

        short8 fa[2], f0[2], f1[2];
        fa[0] = *(const short8*)(pa);
        f0[0] = *(const short8*)(pb0);
        f1[0] = *(const short8*)(pb1);
#pragma unroll
        for (int ks = 0; ks < 16; ++ks) {     // K=256 in steps of 16
            const int cu = ks & 1, nx = cu ^ 1;
            if (ks < 15) {
                fa[nx] = *(const short8*)(pa + (ks + 1) * 16);
                f0[nx] = *(const short8*)(pb0 + (ks + 1) * 16);
                f1[nx] = *(const short8*)(pb1 + (ks + 1) * 16);
            }
            acc[0] = __builtin_amdgcn_mfma_f32_32x32x16_bf16(fa[cu], f0[cu], acc[0], 0, 0, 0);
            acc[1] = __builtin_amdgcn_mfma_f32_32x32x16_bf16(fa[cu], f1[cu], acc[1], 0, 0, 0);
        }

        // Fused epilogue. C/D: col=l31, row=(reg&3)+8*(reg>>2)+4*hi.
#pragma unroll
        for (int tc = 0; tc < 2; ++tc) {
            const int yj = yc[cbl + tc * 32 + l31];
            const int gj = cb0 + cbl + tc * 32 + l31;
#pragma unroll
            for (int reg = 0; reg < 16; ++reg) {
                const int rowm = (reg & 3) + 8 * (reg >> 2) + 4 * hi;
                const int gi = rb + wr * 32 + rowm;
                const int cls = (yp[reg >> 2] >> (8 * (reg & 3))) & 255;
                const bool same = (cls == yj);
                float s = acc[tc][reg];
                float e = __expf(s * (same ? -TINV : TINV));
                rowA[reg] += same ? 0.f : e;
                rowB[reg] += (same && gi != gj) ? e : 0.f;
            }
        }
    }

    // Reduce over the 32 column-lanes (within each 32-lane half).
#pragma unroll
    for (int reg = 0; reg < 16; ++reg) {
#pragma unroll
        for (int off = 1; off < 32; off <<= 1) {
            rowA[reg] += __shfl_xor(rowA[reg], off, 64);
            rowB[reg] += __shfl_xor(rowB[reg], off, 64);
        }
    }
    if (l31 == 0 && wc == 0) {
#pragma unroll
        for (int reg = 0; reg < 16; ++reg) {
            int lr = wr * 32 + (reg & 3) + 8 * (reg >> 2) + 4 * hi;
            mA[lr] = rowA[reg]; mB[lr] = rowB[reg];
        }
    }
    __syncthreads();
    if (l31 == 0 && wc == 1) {
#pragma unroll
        for (int reg = 0; reg < 16; ++reg) {
            int lr = wr * 32 + (reg & 3) + 8 * (reg >> 2) + 4 * hi;
            atomicAdd(&Aacc[rb + lr], rowA[reg] + mA[lr]);
            atomicAdd(&Bacc[rb + lr], rowB[reg] + mB[lr]);
        }
    }
}

// Single block: class histogram in LDS, mean loss, direct write of out[0].
__global__ __launch_bounds__(1024)
void k_final(const float* __restrict__ Aacc, const float* __restrict__ Bacc,
             const int* __restrict__ y, float* __restrict__ out, int n) {
    __shared__ int hist[16];
    __shared__ float red[16];
    const int tid = threadIdx.x;
    if (tid < 16) hist[tid] = 0;
    __syncthreads();
    for (int i = tid; i < n; i += 1024) atomicAdd(&hist[y[i] & 15], 1);
    __syncthreads();
    const float M = __expf(0.5f * TINV);
    float s = 0.f;
    for (int i = tid; i < n; i += 1024) {
        int cc = hist[y[i] & 15];
        float a = (n - cc) > 0 ? Aacc[i] : 1.0f;
        float b = (cc - 1) > 0 ? Bacc[i] : 1.0f;
        s += log1pf(M * a * b);
    }
#pragma unroll
    for (int off = 32; off; off >>= 1) s += __shfl_xor(s, off, 64);
    if ((tid & 63) == 0) red[tid >> 6] = s;
    __syncthreads();
    if (tid == 0) {
        float t = 0.f;
#pragma unroll
        for (int w = 0; w < 16; ++w) t += red[w];
        out[0] = t / (float)n;
    }
}

extern "C" void kernel_launch(void* const* d_in, const int* in_sizes, int n_in,
                              void* d_out, int out_size, void* d_ws, size_t ws_size,
                              hipStream_t stream) {
    const float* P = (const float*)d_in[0];
    const int* y   = (const int*)d_in[1];
    float* out     = (float*)d_out;
    const int n = in_sizes[1];  // 8192

    // ws: Pn bf16 [n*256] | Aacc f32 [n] | Bacc f32 [n]
    unsigned short* Pn = (unsigned short*)d_ws;
    float* Aacc = (float*)((char*)d_ws + (size_t)n * NF * 2);
    float* Bacc = Aacc + n;

    k_prep<<<n / 4, 256, 0, stream>>>(P, Pn, Aacc);
    k_main<<<(n / 128) * (n / 256), 512, 0, stream>>>(Pn, y, Aacc, Bacc);
    k_final<<<1, 1024, 0, stream>>>(Aacc, Bacc, y, out, n);
}

// Round 5
// 238.266 us; speedup vs baseline: 1.1327x; 1.1327x over previous
//
#include <hip/hip_runtime.h>
#include <hip/hip_bf16.h>

// n=8192 rows, d=256 feat, 10 classes.
// loss = mean_i log1p(exp(0.5/0.7) * A_i * B_i)
//   A_i = sum_{j: y_j!=y_i} exp(sim_ij/0.7), B_i = sum_{j!=i: y_j==y_i} exp(-sim_ij/0.7)
//   sim = rownorm(P) @ rownorm(P)^T
//
// R5: m97-structure GEMM (HW-proven 874 TF on gfx950). Global-direct frag
// loads (R2-R4) are latency-bound: 3 loads per 2 MFMAs needs ~13 waves/SIMD
// to hide ~200cyc L2 latency, we have ~3. Fix: global_load_lds width=16
// (fire-and-forget DMA into LDS, no VGPR round-trip), barrier, ds_read_b128
// frags + 16x16x32 MFMA 4x4 acc per 64x64 wave tile. 128x128 block tile,
// BK=64, 4 K-iters, 33KB LDS. Fused R2 epilogue: exp+mask -> register row
// sums -> l15 butterfly -> quad-leader atomics (128 atomic insts/block).

#define NF 256
#define TINV (1.0f / 0.7f)

typedef __attribute__((ext_vector_type(8))) short short8;
typedef __attribute__((ext_vector_type(4))) float float4v;

typedef const __attribute__((address_space(1))) unsigned int glb_u32;
typedef __attribute__((address_space(3))) unsigned int lds_u32;

// One wave per row: normalize to bf16. Also zeroes the accumulators.
__global__ __launch_bounds__(256)
void k_prep(const float* __restrict__ P, unsigned short* __restrict__ Pn,
            float* __restrict__ AB) {  // AB = Aacc||Bacc, 2n floats
    int wave = threadIdx.x >> 6, lane = threadIdx.x & 63;
    int row = blockIdx.x * 4 + wave;
    if (threadIdx.x < 8) AB[blockIdx.x * 8 + threadIdx.x] = 0.f;
    float4 v = *(const float4*)(P + (size_t)row * NF + lane * 4);
    float sq = v.x * v.x + v.y * v.y + v.z * v.z + v.w * v.w;
#pragma unroll
    for (int off = 32; off; off >>= 1) sq += __shfl_xor(sq, off, 64);
    float r = rsqrtf(sq);
    __hip_bfloat16 h0 = __float2bfloat16(v.x * r), h1 = __float2bfloat16(v.y * r),
                   h2 = __float2bfloat16(v.z * r), h3 = __float2bfloat16(v.w * r);
    ushort4 o = { *(unsigned short*)&h0, *(unsigned short*)&h1,
                  *(unsigned short*)&h2, *(unsigned short*)&h3 };
    *(ushort4*)(Pn + (size_t)row * NF + lane * 4) = o;
}

__global__ __launch_bounds__(256)
void k_main(const unsigned short* __restrict__ Pn, const int* __restrict__ y,
            float* __restrict__ Aacc, float* __restrict__ Bacc) {
    // LDS: unpadded [row][k] (global_load_lds forces contiguous lane order)
    __shared__ __align__(16) unsigned short As[128 * 64];
    __shared__ __align__(16) unsigned short Bs[128 * 64];
    __shared__ int yr[128], yc[128];

    const int tid = threadIdx.x;
    const int I = blockIdx.x >> 6, J = blockIdx.x & 63;
    const int rb = I * 128, cb = J * 128;
    if (tid < 128) yr[tid] = y[rb + tid];
    else           yc[tid - 128] = y[cb + tid - 128];

    const int lane = tid & 63, wave = tid >> 6;
    const int quad = lane >> 4, l15 = lane & 15;
    const int wr = wave >> 1, wc = wave & 1;      // 2x2 waves, 64x64 each
    const int srow = lane >> 3, schunk = lane & 7; // staging: 8 rows x 8 chunks

    float4v acc[4][4];
#pragma unroll
    for (int a = 0; a < 4; ++a)
#pragma unroll
        for (int b = 0; b < 4; ++b) acc[a][b] = (float4v){0.f, 0.f, 0.f, 0.f};

#pragma unroll 1
    for (int it = 0; it < 4; ++it) {
        const int k0 = it * 64;
        // Stage A and B panels: per wave 4+4 dwordx4 DMAs (1KB each).
        // Inst covers LDS rows [r8, r8+8); lane L -> row r8+L/8, kchunk L%8.
#pragma unroll
        for (int s = 0; s < 4; ++s) {
            const int r8 = wave * 32 + s * 8;
            const unsigned short* ga =
                Pn + (size_t)(rb + r8 + srow) * NF + k0 + schunk * 8;
            const unsigned short* gb =
                Pn + (size_t)(cb + r8 + srow) * NF + k0 + schunk * 8;
            __builtin_amdgcn_global_load_lds((glb_u32*)ga, (lds_u32*)&As[r8 * 64], 16, 0, 0);
            __builtin_amdgcn_global_load_lds((glb_u32*)gb, (lds_u32*)&Bs[r8 * 64], 16, 0, 0);
        }
        __syncthreads();
#pragma unroll
        for (int ks = 0; ks < 2; ++ks) {          // two k=32 sub-steps
            short8 fa[4], fb[4];
#pragma unroll
            for (int t = 0; t < 4; ++t) {
                fa[t] = *(const short8*)&As[(wr * 64 + t * 16 + l15) * 64 + ks * 32 + quad * 8];
                fb[t] = *(const short8*)&Bs[(wc * 64 + t * 16 + l15) * 64 + ks * 32 + quad * 8];
            }
#pragma unroll
            for (int tr = 0; tr < 4; ++tr)
#pragma unroll
                for (int tc = 0; tc < 4; ++tc)
                    acc[tr][tc] = __builtin_amdgcn_mfma_f32_16x16x32_bf16(
                        fa[tr], fb[tc], acc[tr][tc], 0, 0, 0);
        }
        __syncthreads();
    }

    // Fused epilogue. C/D: col=l15, row=quad*4+reg.
    const int gr0 = rb + wr * 64 + quad * 4;
#pragma unroll
    for (int tr = 0; tr < 4; ++tr) {
        float rowA[4] = {0.f, 0.f, 0.f, 0.f}, rowB[4] = {0.f, 0.f, 0.f, 0.f};
        int yi[4];
#pragma unroll
        for (int r = 0; r < 4; ++r) yi[r] = yr[wr * 64 + tr * 16 + quad * 4 + r];
#pragma unroll
        for (int tc = 0; tc < 4; ++tc) {
            const int jl = wc * 64 + tc * 16 + l15;
            const int yj = yc[jl], gj = cb + jl;
#pragma unroll
            for (int r = 0; r < 4; ++r) {
                float s = acc[tr][tc][r];
                bool same = (yi[r] == yj);
                float e = __expf(s * (same ? -TINV : TINV));
                int gi = gr0 + tr * 16 + r;
                rowA[r] += same ? 0.f : e;
                rowB[r] += (same && gi != gj) ? e : 0.f;
            }
        }
#pragma unroll
        for (int r = 0; r < 4; ++r) {
#pragma unroll
            for (int off = 1; off < 16; off <<= 1) {
                rowA[r] += __shfl_xor(rowA[r], off, 64);
                rowB[r] += __shfl_xor(rowB[r], off, 64);
            }
        }
        if (l15 == 0) {
#pragma unroll
            for (int r = 0; r < 4; ++r) {
                int gi = gr0 + tr * 16 + r;
                atomicAdd(&Aacc[gi], rowA[r]);
                atomicAdd(&Bacc[gi], rowB[r]);
            }
        }
    }
}

// Single block: class histogram in LDS, mean loss, direct write of out[0].
__global__ __launch_bounds__(1024)
void k_final(const float* __restrict__ Aacc, const float* __restrict__ Bacc,
             const int* __restrict__ y, float* __restrict__ out, int n) {
    __shared__ int hist[16];
    __shared__ float red[16];
    const int tid = threadIdx.x;
    if (tid < 16) hist[tid] = 0;
    __syncthreads();
    for (int i = tid; i < n; i += 1024) atomicAdd(&hist[y[i] & 15], 1);
    __syncthreads();
    const float M = __expf(0.5f * TINV);
    float s = 0.f;
    for (int i = tid; i < n; i += 1024) {
        int cc = hist[y[i] & 15];
        float a = (n - cc) > 0 ? Aacc[i] : 1.0f;
        float b = (cc - 1) > 0 ? Bacc[i] : 1.0f;
        s += log1pf(M * a * b);
    }
#pragma unroll
    for (int off = 32; off; off >>= 1) s += __shfl_xor(s, off, 64);
    if ((tid & 63) == 0) red[tid >> 6] = s;
    __syncthreads();
    if (tid == 0) {
        float t = 0.f;
#pragma unroll
        for (int w = 0; w < 16; ++w) t += red[w];
        out[0] = t / (float)n;
    }
}

extern "C" void kernel_launch(void* const* d_in, const int* in_sizes, int n_in,
                              void* d_out, int out_size, void* d_ws, size_t ws_size,
                              hipStream_t stream) {
    const float* P = (const float*)d_in[0];
    const int* y   = (const int*)d_in[1];
    float* out     = (float*)d_out;
    const int n = in_sizes[1];  // 8192

    // ws: Pn bf16 [n*256] | Aacc f32 [n] | Bacc f32 [n]
    unsigned short* Pn = (unsigned short*)d_ws;
    float* Aacc = (float*)((char*)d_ws + (size_t)n * NF * 2);
    float* Bacc = Aacc + n;

    k_prep<<<n / 4, 256, 0, stream>>>(P, Pn, Aacc);
    k_main<<<(n / 128) * (n / 128), 256, 0, stream>>>(Pn, y, Aacc, Bacc);
    k_final<<<1, 1024, 0, stream>>>(Aacc, Bacc, y, out, n);
}

// Round 6
// 170.235 us; speedup vs baseline: 1.5854x; 1.3996x over previous
//
#include <hip/hip_runtime.h>
#include <hip/hip_bf16.h>

// n=8192 rows, d=256 feat, 10 classes.
// loss = mean_i log1p(exp(0.5/0.7) * A_i * B_i)
//   A_i = sum_{j: y_j!=y_i} exp(sim_ij/0.7), B_i = sum_{j!=i: y_j==y_i} exp(-sim_ij/0.7)
//   sim = rownorm(P) @ rownorm(P)^T
//
// R6: K=256 is tiny -> keep A in REGISTERS for the whole block (each wave
// owns 64 rows x K=256 = 128 VGPR of A-frags, loaded once). Only B streams
// through LDS: 64-col chunks (32KB) double-buffered via VGPR round-trip,
// software-pipelined (loads for c+1 issue before compute of c), ONE barrier
// per chunk. XOR swizzle (chunk^=col&7) -> conflict-free B-frag ds_reads.
// Block = 256 rows x 512 cols (4 waves, row-exclusive), grid 512 blocks.
// Fused epilogue accumulates row A/B sums in registers across all chunks;
// one butterfly + 256 atomics per block at the end.

#define NF 256
#define TINV (1.0f / 0.7f)

typedef __attribute__((ext_vector_type(8))) short short8;
typedef __attribute__((ext_vector_type(4))) float float4v;

// One wave per row: normalize to bf16. Also zeroes the accumulators.
__global__ __launch_bounds__(256)
void k_prep(const float* __restrict__ P, unsigned short* __restrict__ Pn,
            float* __restrict__ AB) {  // AB = Aacc||Bacc, 2n floats
    int wave = threadIdx.x >> 6, lane = threadIdx.x & 63;
    int row = blockIdx.x * 4 + wave;
    if (threadIdx.x < 8) AB[blockIdx.x * 8 + threadIdx.x] = 0.f;
    float4 v = *(const float4*)(P + (size_t)row * NF + lane * 4);
    float sq = v.x * v.x + v.y * v.y + v.z * v.z + v.w * v.w;
#pragma unroll
    for (int off = 32; off; off >>= 1) sq += __shfl_xor(sq, off, 64);
    float r = rsqrtf(sq);
    __hip_bfloat16 h0 = __float2bfloat16(v.x * r), h1 = __float2bfloat16(v.y * r),
                   h2 = __float2bfloat16(v.z * r), h3 = __float2bfloat16(v.w * r);
    ushort4 o = { *(unsigned short*)&h0, *(unsigned short*)&h1,
                  *(unsigned short*)&h2, *(unsigned short*)&h3 };
    *(ushort4*)(Pn + (size_t)row * NF + lane * 4) = o;
}

__global__ __launch_bounds__(256, 1)
void k_main(const unsigned short* __restrict__ Pn, const int* __restrict__ y,
            float* __restrict__ Aacc, float* __restrict__ Bacc) {
    // B double-buffer: 64 cols x 256 k, bf16, XOR-swizzled 16B chunks.
    __shared__ __align__(16) unsigned short Bs[2][64 * NF];
    __shared__ int yc[512];

    const int tid = threadIdx.x;
    const int I = blockIdx.x >> 4;        // 32 row panels of 256
    const int G = blockIdx.x & 15;        // 16 col groups of 512
    const int rb = I * 256, cb0 = G * 512;
    const int lane = tid & 63, wave = tid >> 6;
    const int quad = lane >> 4, l15 = lane & 15;

    yc[tid] = y[cb0 + tid];
    yc[256 + tid] = y[cb0 + 256 + tid];

    // A-frags: whole K for this wave's 64 rows. m=l15, k=quad*8+j per 16x16x32.
    const unsigned short* pa = Pn + (size_t)(rb + wave * 64 + l15) * NF + quad * 8;
    short8 afr[4][8];
#pragma unroll
    for (int tr = 0; tr < 4; ++tr)
#pragma unroll
        for (int ks = 0; ks < 8; ++ks)
            afr[tr][ks] = *(const short8*)(pa + (size_t)tr * 16 * NF + ks * 32);

    // Row classes, byte-packed (rows = tr*16 + quad*4 + r).
    unsigned yis[4];
#pragma unroll
    for (int tr = 0; tr < 4; ++tr) {
        int4 v = *(const int4*)(y + rb + wave * 64 + tr * 16 + quad * 4);
        yis[tr] = (unsigned)(v.x & 255) | ((unsigned)(v.y & 255) << 8) |
                  ((unsigned)(v.z & 255) << 16) | ((unsigned)(v.w & 255) << 24);
    }

    float rA[4][4], rB[4][4];
#pragma unroll
    for (int tr = 0; tr < 4; ++tr)
#pragma unroll
        for (int r = 0; r < 4; ++r) { rA[tr][r] = 0.f; rB[tr][r] = 0.f; }

    // B staging: thread covers col sj, 16B-chunks sc0..sc0+7 (128B contiguous).
    const int sj = tid >> 2, sc0 = (tid & 3) * 8;
    const int swm = (sj & 7) * 16;        // write swizzle (bytes)
    uint4 st[8];
#pragma unroll
    for (int i = 0; i < 8; ++i)
        st[i] = *(const uint4*)(Pn + (size_t)(cb0 + sj) * NF + (sc0 + i) * 8);

#pragma unroll 1
    for (int c = 0; c < 8; ++c) {
        char* bsb = (char*)&Bs[c & 1][0];
#pragma unroll
        for (int i = 0; i < 8; ++i)
            *(uint4*)(bsb + sj * 512 + (((sc0 + i) * 16) ^ swm)) = st[i];
        __syncthreads();
        if (c < 7) {
#pragma unroll
            for (int i = 0; i < 8; ++i)
                st[i] = *(const uint4*)(Pn + (size_t)(cb0 + (c + 1) * 64 + sj) * NF + (sc0 + i) * 8);
        }

        float4v acc[4][4];
#pragma unroll
        for (int a = 0; a < 4; ++a)
#pragma unroll
            for (int b = 0; b < 4; ++b) acc[a][b] = (float4v){0.f, 0.f, 0.f, 0.f};

#pragma unroll
        for (int ks = 0; ks < 8; ++ks) {
            short8 fb[4];
#pragma unroll
            for (int tc = 0; tc < 4; ++tc) {
                const int nn = tc * 16 + l15;
                fb[tc] = *(const short8*)(bsb + nn * 512 +
                          ((((ks * 4 + quad) * 16)) ^ ((nn & 7) * 16)));
            }
#pragma unroll
            for (int tr = 0; tr < 4; ++tr)
#pragma unroll
                for (int tc = 0; tc < 4; ++tc)
                    acc[tr][tc] = __builtin_amdgcn_mfma_f32_16x16x32_bf16(
                        afr[tr][ks], fb[tc], acc[tr][tc], 0, 0, 0);
        }

        // Fused epilogue into register row sums. C/D: col=l15, row=quad*4+reg.
#pragma unroll
        for (int tc = 0; tc < 4; ++tc) {
            const int jl = c * 64 + tc * 16 + l15;
            const int yj = yc[jl];
            const int gj = cb0 + jl;
#pragma unroll
            for (int tr = 0; tr < 4; ++tr) {
                const int gi0 = rb + wave * 64 + tr * 16 + quad * 4;
#pragma unroll
                for (int r = 0; r < 4; ++r) {
                    float s = acc[tr][tc][r];
                    const int cls = (yis[tr] >> (8 * r)) & 255;
                    const bool same = (cls == yj);
                    float e = __expf(s * (same ? -TINV : TINV));
                    rA[tr][r] += same ? 0.f : e;
                    rB[tr][r] += (same && (gi0 + r != gj)) ? e : 0.f;
                }
            }
        }
    }

    // Reduce over the 16 col-lanes; quad-leaders do the atomics (rows exclusive).
#pragma unroll
    for (int tr = 0; tr < 4; ++tr)
#pragma unroll
        for (int r = 0; r < 4; ++r) {
#pragma unroll
            for (int off = 1; off < 16; off <<= 1) {
                rA[tr][r] += __shfl_xor(rA[tr][r], off, 64);
                rB[tr][r] += __shfl_xor(rB[tr][r], off, 64);
            }
        }
    if (l15 == 0) {
#pragma unroll
        for (int tr = 0; tr < 4; ++tr)
#pragma unroll
            for (int r = 0; r < 4; ++r) {
                const int gi = rb + wave * 64 + tr * 16 + quad * 4 + r;
                atomicAdd(&Aacc[gi], rA[tr][r]);
                atomicAdd(&Bacc[gi], rB[tr][r]);
            }
    }
}

// Single block: class histogram in LDS, mean loss, direct write of out[0].
__global__ __launch_bounds__(1024)
void k_final(const float* __restrict__ Aacc, const float* __restrict__ Bacc,
             const int* __restrict__ y, float* __restrict__ out, int n) {
    __shared__ int hist[16];
    __shared__ float red[16];
    const int tid = threadIdx.x;
    if (tid < 16) hist[tid] = 0;
    __syncthreads();
    for (int i = tid; i < n; i += 1024) atomicAdd(&hist[y[i] & 15], 1);
    __syncthreads();
    const float M = __expf(0.5f * TINV);
    float s = 0.f;
    for (int i = tid; i < n; i += 1024) {
        int cc = hist[y[i] & 15];
        float a = (n - cc) > 0 ? Aacc[i] : 1.0f;
        float b = (cc - 1) > 0 ? Bacc[i] : 1.0f;
        s += log1pf(M * a * b);
    }
#pragma unroll
    for (int off = 32; off; off >>= 1) s += __shfl_xor(s, off, 64);
    if ((tid & 63) == 0) red[tid >> 6] = s;
    __syncthreads();
    if (tid == 0) {
        float t = 0.f;
#pragma unroll
        for (int w = 0; w < 16; ++w) t += red[w];
        out[0] = t / (float)n;
    }
}

extern "C" void kernel_launch(void* const* d_in, const int* in_sizes, int n_in,
                              void* d_out, int out_size, void* d_ws, size_t ws_size,
                              hipStream_t stream) {
    const float* P = (const float*)d_in[0];
    const int* y   = (const int*)d_in[1];
    float* out     = (float*)d_out;
    const int n = in_sizes[1];  // 8192

    // ws: Pn bf16 [n*256] | Aacc f32 [n] | Bacc f32 [n]
    unsigned short* Pn = (unsigned short*)d_ws;
    float* Aacc = (float*)((char*)d_ws + (size_t)n * NF * 2);
    float* Bacc = Aacc + n;

    k_prep<<<n / 4, 256, 0, stream>>>(P, Pn, Aacc);
    k_main<<<(n / 256) * (n / 512), 256, 0, stream>>>(Pn, y, Aacc, Bacc);
    k_final<<<1, 1024, 0, stream>>>(Aacc, Bacc, y, out, n);
}

// Round 7
// 134.284 us; speedup vs baseline: 2.0099x; 1.2677x over previous
//
#include <hip/hip_runtime.h>
#include <hip/hip_bf16.h>

// n=8192 rows, d=256 feat, 10 classes.
// loss = mean_i log1p(exp(0.5/0.7) * A_i * B_i)
//   A_i = sum_{j: y_j!=y_i} exp(sim_ij/0.7), B_i = sum_{j!=i: y_j==y_i} exp(-sim_ij/0.7)
//   sim = rownorm(P) @ rownorm(P)^T
//
// R7: R6 spilled (FETCH+WRITE 39MB, ~270 reg demand) and had 8-way LDS write
// conflicts (5.2M cyc). Fix: (1) B staged via global_load_lds DMA (zero
// staging VGPRs) into kc-major layout addr(col,kc)=kc*1024+col*16 -- DMA
// writes conflict-free by construction, frag reads land 8 accesses/bank =
// b128 floor (zero conflicts). (2) Wave tile 32x64 (tr=2): afr 64 + acc 32
// AGPR + rowsums 16 => ~144 regs, __launch_bounds__(256,3) -> 3 waves/SIMD,
// 34KB LDS -> 3 blocks/CU. Single-buffer B; cross-block TLP hides DMA drain.
// (3) k_final hist via ballot/popc (R6's LDS-atomic hist serialized ~8192x).

#define NF 256
#define TINV (1.0f / 0.7f)
#define SC2 2.0609929398439434f  // (1/0.7)*log2(e)

typedef __attribute__((ext_vector_type(8))) short short8;
typedef __attribute__((ext_vector_type(4))) float float4v;

typedef const __attribute__((address_space(1))) unsigned int glb_u32;
typedef __attribute__((address_space(3))) unsigned int lds_u32;

// One wave per row: normalize to bf16. Also zeroes the accumulators.
__global__ __launch_bounds__(256)
void k_prep(const float* __restrict__ P, unsigned short* __restrict__ Pn,
            float* __restrict__ AB) {  // AB = Aacc||Bacc, 2n floats
    int wave = threadIdx.x >> 6, lane = threadIdx.x & 63;
    int row = blockIdx.x * 4 + wave;
    if (threadIdx.x < 8) AB[blockIdx.x * 8 + threadIdx.x] = 0.f;
    float4 v = *(const float4*)(P + (size_t)row * NF + lane * 4);
    float sq = v.x * v.x + v.y * v.y + v.z * v.z + v.w * v.w;
#pragma unroll
    for (int off = 32; off; off >>= 1) sq += __shfl_xor(sq, off, 64);
    float r = rsqrtf(sq);
    __hip_bfloat16 h0 = __float2bfloat16(v.x * r), h1 = __float2bfloat16(v.y * r),
                   h2 = __float2bfloat16(v.z * r), h3 = __float2bfloat16(v.w * r);
    ushort4 o = { *(unsigned short*)&h0, *(unsigned short*)&h1,
                  *(unsigned short*)&h2, *(unsigned short*)&h3 };
    *(ushort4*)(Pn + (size_t)row * NF + lane * 4) = o;
}

__global__ __launch_bounds__(256, 3)
void k_main(const unsigned short* __restrict__ Pn, const int* __restrict__ y,
            float* __restrict__ Aacc, float* __restrict__ Bacc) {
    // B chunk: 64 cols x K=256, kc-major: ushort addr = kc*512 + col*8
    __shared__ __align__(16) unsigned short Bs[64 * NF];
    __shared__ int yc[512];

    const int tid = threadIdx.x;
    const int I = blockIdx.x >> 4;        // 64 row panels of 128
    const int G = blockIdx.x & 15;        // 16 col groups of 512
    const int rb = I * 128, cb0 = G * 512;
    const int lane = tid & 63, wave = tid >> 6;
    const int quad = lane >> 4, l15 = lane & 15;

    yc[tid] = y[cb0 + tid];
    yc[256 + tid] = y[cb0 + 256 + tid];

    // A-frags: this wave's 32 rows x full K. m=l15, k=quad*8+j (16x16x32).
    const unsigned short* pa = Pn + (size_t)(rb + wave * 32 + l15) * NF + quad * 8;
    short8 afr[2][8];
#pragma unroll
    for (int tr = 0; tr < 2; ++tr)
#pragma unroll
        for (int ks = 0; ks < 8; ++ks)
            afr[tr][ks] = *(const short8*)(pa + (size_t)tr * 16 * NF + ks * 32);

    // Row classes byte-packed (rows tr*16 + quad*4 + r).
    unsigned yis[2];
#pragma unroll
    for (int tr = 0; tr < 2; ++tr) {
        int4 v = *(const int4*)(y + rb + wave * 32 + tr * 16 + quad * 4);
        yis[tr] = (unsigned)(v.x & 255) | ((unsigned)(v.y & 255) << 8) |
                  ((unsigned)(v.z & 255) << 16) | ((unsigned)(v.w & 255) << 24);
    }

    float rA[2][4], rB[2][4];
#pragma unroll
    for (int tr = 0; tr < 2; ++tr)
#pragma unroll
        for (int r = 0; r < 4; ++r) { rA[tr][r] = 0.f; rB[tr][r] = 0.f; }

    // DMA one 64-col chunk: 32 instrs (8 per wave), lane L -> col L.
    // kc-instr: lane L reads Pn[(cb0+c*64+L)*NF + kc*8], lands at kc*1024+L*16.
#define DMA_CHUNK(c)                                                          \
    {                                                                         \
        _Pragma("unroll")                                                     \
        for (int i = 0; i < 8; ++i) {                                         \
            const int kc = wave * 8 + i;                                      \
            const unsigned short* src =                                       \
                Pn + (size_t)(cb0 + (c) * 64 + lane) * NF + kc * 8;           \
            __builtin_amdgcn_global_load_lds((glb_u32*)src,                   \
                (lds_u32*)&Bs[kc * 512], 16, 0, 0);                           \
        }                                                                     \
    }

    DMA_CHUNK(0)

#pragma unroll 1
    for (int c = 0; c < 8; ++c) {
        __syncthreads();   // own-vmcnt drained by compiler before barrier -> Bs ready

        float4v acc[2][4];
#pragma unroll
        for (int a = 0; a < 2; ++a)
#pragma unroll
            for (int b = 0; b < 4; ++b) acc[a][b] = (float4v){0.f, 0.f, 0.f, 0.f};

#pragma unroll
        for (int ks = 0; ks < 8; ++ks) {
            short8 fb[4];
#pragma unroll
            for (int tc = 0; tc < 4; ++tc)
                fb[tc] = *(const short8*)&Bs[(ks * 4 + quad) * 512 + (tc * 16 + l15) * 8];
#pragma unroll
            for (int tr = 0; tr < 2; ++tr)
#pragma unroll
                for (int tc = 0; tc < 4; ++tc)
                    acc[tr][tc] = __builtin_amdgcn_mfma_f32_16x16x32_bf16(
                        afr[tr][ks], fb[tc], acc[tr][tc], 0, 0, 0);
        }
        __syncthreads();   // all waves done reading Bs
        if (c < 7) DMA_CHUNK(c + 1)

        // Fused epilogue. C/D: col=l15, row=quad*4+reg.
#pragma unroll
        for (int tc = 0; tc < 4; ++tc) {
            const int jl = c * 64 + tc * 16 + l15;
            const int yj = yc[jl];
            const int gj = cb0 + jl;
#pragma unroll
            for (int tr = 0; tr < 2; ++tr) {
                const int gi0 = rb + wave * 32 + tr * 16 + quad * 4;
#pragma unroll
                for (int r = 0; r < 4; ++r) {
                    const float s = acc[tr][tc][r];
                    const int cls = (yis[tr] >> (8 * r)) & 255;
                    const bool same = (cls == yj);
                    const float e = exp2f(s * (same ? -SC2 : SC2));
                    rA[tr][r] += same ? 0.f : e;
                    rB[tr][r] += (same && (gi0 + r != gj)) ? e : 0.f;
                }
            }
        }
    }

    // Butterfly over 16 col-lanes; quad leaders issue atomics (rows exclusive).
#pragma unroll
    for (int tr = 0; tr < 2; ++tr)
#pragma unroll
        for (int r = 0; r < 4; ++r) {
#pragma unroll
            for (int off = 1; off < 16; off <<= 1) {
                rA[tr][r] += __shfl_xor(rA[tr][r], off, 64);
                rB[tr][r] += __shfl_xor(rB[tr][r], off, 64);
            }
        }
    if (l15 == 0) {
#pragma unroll
        for (int tr = 0; tr < 2; ++tr)
#pragma unroll
            for (int r = 0; r < 4; ++r) {
                const int gi = rb + wave * 32 + tr * 16 + quad * 4 + r;
                atomicAdd(&Aacc[gi], rA[tr][r]);
                atomicAdd(&Bacc[gi], rB[tr][r]);
            }
    }
}

// Single block: ballot-based class histogram (no atomic serialization),
// mean loss, direct write of out[0].
__global__ __launch_bounds__(1024)
void k_final(const float* __restrict__ Aacc, const float* __restrict__ Bacc,
             const int* __restrict__ y, float* __restrict__ out, int n) {
    __shared__ int hist[16];
    __shared__ float red[16];
    const int tid = threadIdx.x;
    if (tid < 16) hist[tid] = 0;
    __syncthreads();
    int loc[10];
#pragma unroll
    for (int cc = 0; cc < 10; ++cc) loc[cc] = 0;
    for (int i = tid; i < n; i += 1024) {
        const int yv = y[i];
#pragma unroll
        for (int cc = 0; cc < 10; ++cc) {
            unsigned long long m = __ballot(yv == cc);
            if ((tid & 63) == 0) loc[cc] += __popcll(m);
        }
    }
    if ((tid & 63) == 0)
#pragma unroll
        for (int cc = 0; cc < 10; ++cc) atomicAdd(&hist[cc], loc[cc]);
    __syncthreads();
    const float M = __expf(0.5f * TINV);
    float s = 0.f;
    for (int i = tid; i < n; i += 1024) {
        const int cc = hist[y[i] & 15];
        const float a = (n - cc) > 0 ? Aacc[i] : 1.0f;
        const float b = (cc - 1) > 0 ? Bacc[i] : 1.0f;
        s += log1pf(M * a * b);
    }
#pragma unroll
    for (int off = 32; off; off >>= 1) s += __shfl_xor(s, off, 64);
    if ((tid & 63) == 0) red[tid >> 6] = s;
    __syncthreads();
    if (tid == 0) {
        float t = 0.f;
#pragma unroll
        for (int w = 0; w < 16; ++w) t += red[w];
        out[0] = t / (float)n;
    }
}

extern "C" void kernel_launch(void* const* d_in, const int* in_sizes, int n_in,
                              void* d_out, int out_size, void* d_ws, size_t ws_size,
                              hipStream_t stream) {
    const float* P = (const float*)d_in[0];
    const int* y   = (const int*)d_in[1];
    float* out     = (float*)d_out;
    const int n = in_sizes[1];  // 8192

    // ws: Pn bf16 [n*256] | Aacc f32 [n] | Bacc f32 [n]
    unsigned short* Pn = (unsigned short*)d_ws;
    float* Aacc = (float*)((char*)d_ws + (size_t)n * NF * 2);
    float* Bacc = Aacc + n;

    k_prep<<<n / 4, 256, 0, stream>>>(P, Pn, Aacc);
    k_main<<<(n / 128) * (n / 512), 256, 0, stream>>>(Pn, y, Aacc, Bacc);
    k_final<<<1, 1024, 0, stream>>>(Aacc, Bacc, y, out, n);
}